// Round 3
// baseline (19058.699 us; speedup 1.0000x reference)
//
#include <hip/hip_runtime.h>
#include <hip/hip_bf16.h>
#include <cstdint>
#include <cmath>

typedef unsigned short u16;
typedef unsigned int u32;

// ---- model dims ----
#define B_    8
#define T_IN  2048
#define CIN1  273
#define L1_   1025
#define L_    513
#define C_    512
#define CE_   576
#define M1_   (B_*L1_)   /* 8200 */
#define M_    (B_*L_)    /* 4104 */
#define K1_   (CIN1*4)   /* 1092 */
#define H_    8
#define D_    64
#define R_    50
#define NBLK_LSTM 128

// ======================= generic GEMM: C[m,n] = sum_k A[m,k]*B[n,k] + bias =======================
__device__ __forceinline__ float a_load(const void* A, int m, int k, int lda, int amode) {
    if (amode == 0) {
        return ((const float*)A)[(size_t)m * lda + k];
    } else if (amode == 2) {
        int b = m / L1_, t = m - b * L1_;
        int ci = k >> 2, kk = k & 3;
        int it = 2 * t - 2 + kk;
        if ((unsigned)it >= (unsigned)T_IN) return 0.f;
        return ((const float*)A)[((size_t)(b * CIN1 + ci)) * T_IN + it];
    } else {
        int b = m / L_, t = m - b * L_;
        int ci = k >> 2, kk = k & 3;
        int it = 2 * t - 2 + kk;
        if ((unsigned)it >= (unsigned)L1_) return 0.f;
        return ((const float*)A)[((size_t)(b * L1_ + it)) * C_ + ci];
    }
}

__global__ __launch_bounds__(256) void gemm_kernel(
    const void* __restrict__ Aptr, const float* __restrict__ Bptr,
    const float* __restrict__ bias1, const float* __restrict__ bias2,
    float* __restrict__ Cf,
    int Msz, int Nsz, int Ksz, int lda, int ldc, int amode, int cmode, int relu)
{
    __shared__ float As[16][68];
    __shared__ float Bs[16][68];
    int tid = threadIdx.x;
    int tx = tid & 15, ty = tid >> 4;
    int kq = tid & 15, mq = tid >> 4;
    int m0 = blockIdx.x * 64, n0 = blockIdx.y * 64;

    float acc[4][4];
#pragma unroll
    for (int i = 0; i < 4; ++i)
#pragma unroll
        for (int j = 0; j < 4; ++j) acc[i][j] = 0.f;

    for (int k0 = 0; k0 < Ksz; k0 += 16) {
        int k = k0 + kq;
#pragma unroll
        for (int j = 0; j < 4; ++j) {
            int rl = mq + 16 * j;
            int m = m0 + rl;
            float av = 0.f;
            if (m < Msz && k < Ksz) av = a_load(Aptr, m, k, lda, amode);
            As[kq][rl] = av;
            float bv = 0.f;
            if (k < Ksz) bv = Bptr[(size_t)(n0 + rl) * Ksz + k];
            Bs[kq][rl] = bv;
        }
        __syncthreads();
#pragma unroll
        for (int kk = 0; kk < 16; ++kk) {
            float a4[4], b4[4];
            *(float4*)a4 = *(const float4*)&As[kk][ty * 4];
            *(float4*)b4 = *(const float4*)&Bs[kk][tx * 4];
#pragma unroll
            for (int i = 0; i < 4; ++i)
#pragma unroll
                for (int j = 0; j < 4; ++j) acc[i][j] += a4[i] * b4[j];
        }
        __syncthreads();
    }

#pragma unroll
    for (int i = 0; i < 4; ++i) {
        int m = m0 + ty * 4 + i;
        if (m >= Msz) continue;
#pragma unroll
        for (int j = 0; j < 4; ++j) {
            int n = n0 + tx * 4 + j;
            float v = acc[i][j] + bias1[n] + (bias2 ? bias2[n] : 0.f);
            if (relu) v = fmaxf(v, 0.f);
            if (cmode == 0) {
                Cf[(size_t)m * ldc + n] = v;
            } else {
                int b = m / L_, t = m - b * L_;
                Cf[((size_t)(b * 128 + n)) * L_ + t] = v;
            }
        }
    }
}

// ======================= subject embedding concat =======================
__global__ __launch_bounds__(256) void emb_kernel(const float* __restrict__ semb,
                                                  const int* __restrict__ subj,
                                                  float* __restrict__ x2bt)
{
    int idx = blockIdx.x * 256 + threadIdx.x;
    if (idx >= M_ * 64) return;
    int m = idx >> 6, e = idx & 63;
    int b = m / L_;
    x2bt[(size_t)m * CE_ + 512 + e] = semb[subj[b] * 64 + e];
}

// ======================= persistent LSTM layer =======================
// 128 blocks x 256 threads. Block owns hidden units j = blk*4 .. blk*4+3 (all 4 gates, all 8 batches).
// Weights register-cached (64 floats/thread). One device-scope grid barrier per timestep.
// pre[(b*L+t)*2048 + g*512 + j] holds x*Wih + bih + bhh. Whh is [2048][512] row-major.
__global__ __launch_bounds__(256) void lstm_persistent(const float* __restrict__ pre,
                                                       const float* __restrict__ Whh,
                                                       float* __restrict__ hseq,
                                                       u32* __restrict__ bar)
{
    __shared__ float hsT[512][12];     // h(t-1) transposed: [c][b], pad to 12
    __shared__ float red[4][8][16];    // per-wave partials
    __shared__ float gates[4][4][8];   // [jj][g][b]
    __shared__ float cl[4][8];         // cell state [jj][b]

    int tid = threadIdx.x;
    int blk = blockIdx.x;
    int csplit = tid >> 3;             // 0..31
    int rowg   = (tid >> 1) & 3;       // jj this thread computes
    int bg     = tid & 1;              // batch group (4 batches)

    // register-cache weights: w4[cc] = (gate0..3) weight at c = csplit + 32*cc for j = blk*4+rowg
    float4 w4[16];
    {
        const float* wb = Whh + ((size_t)(blk * 4 + rowg)) * 512 + csplit;
#pragma unroll
        for (int cc = 0; cc < 16; ++cc) {
            int c32 = 32 * cc;
            w4[cc].x = wb[c32];
            w4[cc].y = wb[c32 + 512 * 512];
            w4[cc].z = wb[c32 + 2 * 512 * 512];
            w4[cc].w = wb[c32 + 3 * 512 * 512];
        }
    }
    if (tid < 32) cl[tid >> 3][tid & 7] = 0.f;

    int f_jj = tid >> 5, f_g = (tid >> 3) & 3, f_b = tid & 7;   // final-stage mapping (tid<128)

    unsigned gen = 0;
    for (int t = 0; t < L_; ++t) {
        // ---- stage h(t-1) ----
        if (t == 0) {
            for (int idx = tid; idx < 4096; idx += 256)
                hsT[idx >> 3][idx & 7] = 0.f;
        } else {
            for (int idx = tid; idx < 4096; idx += 256) {
                int b = idx >> 9, c = idx & 511;
                hsT[c][b] = hseq[((size_t)(b * L_ + (t - 1))) * 512 + c];
            }
        }
        float mypre = 0.f;
        if (tid < 128)
            mypre = pre[((size_t)(f_b * L_ + t)) * 2048 + f_g * 512 + blk * 4 + f_jj];
        __syncthreads();

        // ---- matvec partials: acc[g][b4] over this thread's 16 c values ----
        float acc[4][4] = {{0.f,0.f,0.f,0.f},{0.f,0.f,0.f,0.f},{0.f,0.f,0.f,0.f},{0.f,0.f,0.f,0.f}};
#pragma unroll
        for (int cc = 0; cc < 16; ++cc) {
            int c = csplit + 32 * cc;
            float4 hv = *(const float4*)&hsT[c][bg * 4];
            float hb[4] = {hv.x, hv.y, hv.z, hv.w};
            float wg[4] = {w4[cc].x, w4[cc].y, w4[cc].z, w4[cc].w};
#pragma unroll
            for (int g = 0; g < 4; ++g)
#pragma unroll
                for (int b4 = 0; b4 < 4; ++b4)
                    acc[g][b4] = fmaf(wg[g], hb[b4], acc[g][b4]);
        }

        // ---- reduce over csplit: intra-wave (lane bits 3..5) ----
#pragma unroll
        for (int m = 8; m <= 32; m <<= 1)
#pragma unroll
            for (int g = 0; g < 4; ++g)
#pragma unroll
                for (int b4 = 0; b4 < 4; ++b4)
                    acc[g][b4] += __shfl_xor(acc[g][b4], m);
        int lane = tid & 63;
        if (lane < 8) {
            int w = tid >> 6;
#pragma unroll
            for (int g = 0; g < 4; ++g)
#pragma unroll
                for (int b4 = 0; b4 < 4; ++b4)
                    red[w][lane][g * 4 + b4] = acc[g][b4];
        }
        __syncthreads();

        // ---- cross-wave sum + pre ----
        if (tid < 128) {
            int gidx = f_jj * 2 + (f_b >> 2);
            int vi = f_g * 4 + (f_b & 3);
            gates[f_jj][f_g][f_b] = red[0][gidx][vi] + red[1][gidx][vi]
                                  + red[2][gidx][vi] + red[3][gidx][vi] + mypre;
        }
        __syncthreads();

        // ---- gate math + h write ----
        if (tid < 32) {
            int jj = tid >> 3, b = tid & 7;
            float gi = gates[jj][0][b], gf = gates[jj][1][b];
            float gg = gates[jj][2][b], go = gates[jj][3][b];
            float cprev = cl[jj][b];
            float si = 1.f / (1.f + expf(-gi));
            float sf = 1.f / (1.f + expf(-gf));
            float so = 1.f / (1.f + expf(-go));
            float cn = sf * cprev + si * tanhf(gg);
            cl[jj][b] = cn;
            hseq[((size_t)(b * L_ + t)) * 512 + blk * 4 + jj] = so * tanhf(cn);
        }

        // ---- grid barrier (sense via monotone generation counter) ----
        __threadfence();
        __syncthreads();
        if (tid == 0) {
            unsigned a = __hip_atomic_fetch_add(&bar[0], 1u, __ATOMIC_ACQ_REL, __HIP_MEMORY_SCOPE_AGENT);
            if (a == NBLK_LSTM - 1) {
                __hip_atomic_store(&bar[0], 0u, __ATOMIC_RELAXED, __HIP_MEMORY_SCOPE_AGENT);
                __hip_atomic_store(&bar[1], gen + 1, __ATOMIC_RELEASE, __HIP_MEMORY_SCOPE_AGENT);
            } else {
                while (__hip_atomic_load(&bar[1], __ATOMIC_ACQUIRE, __HIP_MEMORY_SCOPE_AGENT) <= gen)
                    __builtin_amdgcn_s_sleep(1);
            }
        }
        gen++;
        __syncthreads();
    }
}

// ======================= banded attention (radius 50) =======================
__global__ __launch_bounds__(128) void attn_kernel(const float* __restrict__ q,
                                                   const float* __restrict__ k,
                                                   const float* __restrict__ cnt,
                                                   const float* __restrict__ rel,
                                                   float* __restrict__ out)
{
    int t = blockIdx.x, h = blockIdx.y, b = blockIdx.z;
    int s_lo = max(0, t - R_), s_hi = min(L_ - 1, t + R_);
    int W = s_hi - s_lo + 1;
    int tid = threadIdx.x;

    __shared__ float qrow[64];
    __shared__ float dots[104];
    __shared__ float red[128];

    const float* qp = q + ((size_t)(b * L_ + t) * C_ + h * D_);
    if (tid < 64) qrow[tid] = qp[tid];
    __syncthreads();

    if (tid < W) {
        int s = s_lo + tid;
        const float* kp = k + ((size_t)(b * L_ + s) * C_ + h * D_);
        const float* rp = rel + (R_ + t - s) * D_;
        float acc = 0.f;
#pragma unroll 8
        for (int d = 0; d < 64; ++d)
            acc += qrow[d] * (kp[d] + 0.3f * rp[d]);
        dots[tid] = acc;
    }
    __syncthreads();

    red[tid] = (tid < W) ? dots[tid] : -INFINITY;
    __syncthreads();
    for (int s = 64; s > 0; s >>= 1) {
        if (tid < s) red[tid] = fmaxf(red[tid], red[tid + s]);
        __syncthreads();
    }
    float mx = red[0];
    __syncthreads();
    float e = 0.f;
    if (tid < W) { e = expf(dots[tid] - mx); dots[tid] = e; }
    red[tid] = e;
    __syncthreads();
    for (int s = 64; s > 0; s >>= 1) {
        if (tid < s) red[tid] += red[tid + s];
        __syncthreads();
    }
    float inv = 1.f / red[0];
    if (tid < W) dots[tid] *= inv;
    __syncthreads();

    if (tid < 64) {
        float acc = 0.f;
        const float* cb = cnt + ((size_t)(b * L_ + s_lo) * C_ + h * D_ + tid);
        const float* rb = rel + (R_ + t - s_lo) * D_ + tid;
        for (int i = 0; i < W; ++i)
            acc += dots[i] * (cb[(size_t)i * C_] + 0.3f * rb[-i * D_]);
        out[(size_t)(b * L_ + t) * C_ + h * D_ + tid] = acc;
    }
}

// ======================= BatchNorm training stats =======================
__global__ __launch_bounds__(256) void bn_stats(const float* __restrict__ fcout, float* __restrict__ stats)
{
    int o = blockIdx.x;
    int tid = threadIdx.x;
    float s = 0.f, ss = 0.f;
    for (int m = tid; m < M_; m += 256) {
        float v = fcout[(size_t)m * 512 + o];
        s += v; ss += v * v;
    }
    __shared__ float rs[256], rq[256];
    rs[tid] = s; rq[tid] = ss;
    __syncthreads();
    for (int k = 128; k > 0; k >>= 1) {
        if (tid < k) { rs[tid] += rs[tid + k]; rq[tid] += rq[tid + k]; }
        __syncthreads();
    }
    if (tid == 0) {
        float mean = rs[0] / (float)M_;
        float var = rq[0] / (float)M_ - mean * mean;
        stats[o] = mean;
        stats[512 + o] = rsqrtf(fmaxf(var, 0.f) + 1e-5f);
    }
}

// ======================= BN apply + ReLU + scale + residual =======================
__global__ __launch_bounds__(256) void bn_apply(const float* __restrict__ fcout,
                                                const float* __restrict__ stats,
                                                const float* __restrict__ bng, const float* __restrict__ bnb,
                                                const float* __restrict__ ascl,
                                                float* __restrict__ xres)
{
    int idx = blockIdx.x * 256 + threadIdx.x;
    if (idx >= M_ * 512) return;
    int c = idx & 511;
    float v = (fcout[idx] - stats[c]) * stats[512 + c] * bng[c] + bnb[c];
    v = fmaxf(v, 0.f) * ascl[c];
    xres[idx] += v;
}

// ======================= host launch =======================
extern "C" void kernel_launch(void* const* d_in, const int* in_sizes, int n_in,
                              void* d_out, int out_size, void* d_ws, size_t ws_size,
                              hipStream_t stream)
{
    const float* meg  = (const float*)d_in[0];
    const float* w1   = (const float*)d_in[1];
    const float* b1   = (const float*)d_in[2];
    const float* w2   = (const float*)d_in[3];
    const float* b2   = (const float*)d_in[4];
    const float* semb = (const float*)d_in[5];
    const float* Wih0 = (const float*)d_in[6];
    const float* Whh0 = (const float*)d_in[7];
    const float* bih0 = (const float*)d_in[8];
    const float* bhh0 = (const float*)d_in[9];
    const float* Wih1 = (const float*)d_in[10];
    const float* Whh1 = (const float*)d_in[11];
    const float* bih1 = (const float*)d_in[12];
    const float* bhh1 = (const float*)d_in[13];
    const float* qw   = (const float*)d_in[14];
    const float* qb   = (const float*)d_in[15];
    const float* kw   = (const float*)d_in[16];
    const float* kb   = (const float*)d_in[17];
    const float* cw   = (const float*)d_in[18];
    const float* cbi  = (const float*)d_in[19];
    const float* rel  = (const float*)d_in[20];
    const float* fcw  = (const float*)d_in[21];
    const float* fcb  = (const float*)d_in[22];
    const float* bng  = (const float*)d_in[23];
    const float* bnb  = (const float*)d_in[24];
    const float* ascl = (const float*)d_in[25];
    const float* outw = (const float*)d_in[26];
    const float* outb = (const float*)d_in[27];
    const int* subj = (const int*)d_in[28];
    float* out = (float*)d_out;

    float* ws = (float*)d_ws;
    // arena (float offsets)
    float* x1    = ws + 0;          // [8200][512]   -> 4,198,400
    float* x2bt  = ws + 4198400;    // [4104][576]   -> 6,562,304
    float* pre   = ws + 6562304;    // [4104][2048]  -> 14,967,296
    float* h0    = ws + 14967296;   // [4104][512]   -> 17,068,544
    float* h1    = ws + 17068544;   // [4104][512]   -> 19,169,792
    u32*   bar   = (u32*)(ws + 19169792);  // 8 u32 barrier (2 layers x 2 words)
    // overlays (dead buffers reused):
    float* qb_f  = ws + 0;          // q  [4104][512] over x1
    float* kb_f  = ws + 2101248;    // k
    float* cb_f  = ws + 4202496;    // cnt (spills into dead x2bt region)
    float* attno = ws + 6562304;    // over pre (dead after LSTM layer 1)
    float* fco   = ws + 8663552;
    float* stats = ws + 10764800;   // 1024 floats

    auto gemm = [&](const void* A, const float* Bw, const float* bi1, const float* bi2,
                    float* Cf, int Msz, int Nsz, int Ksz,
                    int lda, int ldc, int amode, int cmode, int relu) {
        dim3 g((Msz + 63) / 64, Nsz / 64);
        gemm_kernel<<<g, 256, 0, stream>>>(A, Bw, bi1, bi2, Cf,
                                           Msz, Nsz, Ksz, lda, ldc, amode, cmode, relu);
    };

    // zero the grid-barrier words (capturable async memset)
    hipMemsetAsync(bar, 0, 8 * sizeof(u32), stream);

    // conv1 (im2col from meg) -> x1 [b*1025+t][512], relu
    gemm(meg, w1, b1, nullptr, x1, M1_, 512, K1_, 0, 512, 2, 0, 1);
    // conv2 (im2col from x1) -> x2bt [b*513+t][576] cols 0..511, relu
    gemm(x1, w2, b2, nullptr, x2bt, M_, 512, 2048, 0, CE_, 3, 0, 1);
    // subject embedding -> cols 512..575
    emb_kernel<<<(M_ * 64 + 255) / 256, 256, 0, stream>>>(semb, subj, x2bt);

    // LSTM layer 0: pre-GEMM + persistent recurrence
    gemm(x2bt, Wih0, bih0, bhh0, pre, M_, 2048, CE_, CE_, 2048, 0, 0, 0);
    lstm_persistent<<<NBLK_LSTM, 256, 0, stream>>>(pre, Whh0, h0, bar);
    // LSTM layer 1
    gemm(h0, Wih1, bih1, bhh1, pre, M_, 2048, 512, 512, 2048, 0, 0, 0);
    lstm_persistent<<<NBLK_LSTM, 256, 0, stream>>>(pre, Whh1, h1, bar + 4);

    // attention projections
    gemm(h1, qw, qb, nullptr, qb_f, M_, 512, 512, 512, 512, 0, 0, 0);
    gemm(h1, kw, kb, nullptr, kb_f, M_, 512, 512, 512, 512, 0, 0, 0);
    gemm(h1, cw, cbi, nullptr, cb_f, M_, 512, 512, 512, 512, 0, 0, 0);

    attn_kernel<<<dim3(L_, H_, B_), 128, 0, stream>>>(qb_f, kb_f, cb_f, rel, attno);

    // fc + BN(train) + relu*scale + residual into h1
    gemm(attno, fcw, fcb, nullptr, fco, M_, 512, 512, 512, 512, 0, 0, 0);
    bn_stats<<<512, 256, 0, stream>>>(fco, stats);
    bn_apply<<<(M_ * 512 + 255) / 256, 256, 0, stream>>>(fco, stats, bng, bnb, ascl, h1);

    // final projection -> d_out [b][128][t] fp32
    gemm(h1, outw, outb, nullptr, out, M_, 128, 512, 512, 0, 0, 1, 0);
}

// Round 4
// 8933.224 us; speedup vs baseline: 2.1335x; 2.1335x over previous
//
#include <hip/hip_runtime.h>
#include <cstdint>
#include <cmath>

typedef unsigned short u16;
typedef unsigned int u32;

// ---- model dims ----
#define B_    8
#define T_IN  2048
#define CIN1  273
#define L1_   1025
#define L_    513
#define C_    512
#define CE_   576
#define M1_   (B_*L1_)   /* 8200 */
#define M_    (B_*L_)    /* 4104 */
#define K1_   (CIN1*4)   /* 1092 */
#define H_    8
#define D_    64
#define R_    50

// ======================= generic GEMM: C[m,n] = sum_k A[m,k]*B[n,k] + bias =======================
// amode: 0 = fp32 row-major A (lda), 2 = conv1 im2col from meg, 3 = conv2 im2col from x1
// cmode: 0 = C[m*ldc+n]; 1 = out[b][n][t] (n<128); 2 = C[(t*8+b)*ldc+n] (time-major)
__device__ __forceinline__ float a_load(const void* A, int m, int k, int lda, int amode) {
    if (amode == 0) {
        return ((const float*)A)[(size_t)m * lda + k];
    } else if (amode == 2) {
        int b = m / L1_, t = m - b * L1_;
        int ci = k >> 2, kk = k & 3;
        int it = 2 * t - 2 + kk;
        if ((unsigned)it >= (unsigned)T_IN) return 0.f;
        return ((const float*)A)[((size_t)(b * CIN1 + ci)) * T_IN + it];
    } else {
        int b = m / L_, t = m - b * L_;
        int ci = k >> 2, kk = k & 3;
        int it = 2 * t - 2 + kk;
        if ((unsigned)it >= (unsigned)L1_) return 0.f;
        return ((const float*)A)[((size_t)(b * L1_ + it)) * C_ + ci];
    }
}

__global__ __launch_bounds__(256) void gemm_kernel(
    const void* __restrict__ Aptr, const float* __restrict__ Bptr,
    const float* __restrict__ bias1, const float* __restrict__ bias2,
    float* __restrict__ Cf,
    int Msz, int Nsz, int Ksz, int lda, int ldc, int amode, int cmode, int relu)
{
    __shared__ float As[16][68];
    __shared__ float Bs[16][68];
    int tid = threadIdx.x;
    int tx = tid & 15, ty = tid >> 4;
    int kq = tid & 15, mq = tid >> 4;
    int m0 = blockIdx.x * 64, n0 = blockIdx.y * 64;

    float acc[4][4];
#pragma unroll
    for (int i = 0; i < 4; ++i)
#pragma unroll
        for (int j = 0; j < 4; ++j) acc[i][j] = 0.f;

    for (int k0 = 0; k0 < Ksz; k0 += 16) {
        int k = k0 + kq;
#pragma unroll
        for (int j = 0; j < 4; ++j) {
            int rl = mq + 16 * j;
            int m = m0 + rl;
            float av = 0.f;
            if (m < Msz && k < Ksz) av = a_load(Aptr, m, k, lda, amode);
            As[kq][rl] = av;
            float bv = 0.f;
            if (k < Ksz) bv = Bptr[(size_t)(n0 + rl) * Ksz + k];
            Bs[kq][rl] = bv;
        }
        __syncthreads();
#pragma unroll
        for (int kk = 0; kk < 16; ++kk) {
            float a4[4], b4[4];
            *(float4*)a4 = *(const float4*)&As[kk][ty * 4];
            *(float4*)b4 = *(const float4*)&Bs[kk][tx * 4];
#pragma unroll
            for (int i = 0; i < 4; ++i)
#pragma unroll
                for (int j = 0; j < 4; ++j) acc[i][j] += a4[i] * b4[j];
        }
        __syncthreads();
    }

#pragma unroll
    for (int i = 0; i < 4; ++i) {
        int m = m0 + ty * 4 + i;
        if (m >= Msz) continue;
#pragma unroll
        for (int j = 0; j < 4; ++j) {
            int n = n0 + tx * 4 + j;
            float v = acc[i][j] + bias1[n] + (bias2 ? bias2[n] : 0.f);
            if (relu) v = fmaxf(v, 0.f);
            if (cmode == 0) {
                Cf[(size_t)m * ldc + n] = v;
            } else if (cmode == 1) {
                int b = m / L_, t = m - b * L_;
                Cf[((size_t)(b * 128 + n)) * L_ + t] = v;
            } else {
                int b = m / L_, t = m - b * L_;
                Cf[((size_t)(t * 8 + b)) * ldc + n] = v;
            }
        }
    }
}

// ======================= subject embedding concat =======================
__global__ __launch_bounds__(256) void emb_kernel(const float* __restrict__ semb,
                                                  const int* __restrict__ subj,
                                                  float* __restrict__ x2bt)
{
    int idx = blockIdx.x * 256 + threadIdx.x;
    if (idx >= M_ * 64) return;
    int m = idx >> 6, e = idx & 63;
    int b = m / L_;
    x2bt[(size_t)m * CE_ + 512 + e] = semb[subj[b] * 64 + e];
}

// ======================= fused 2-layer LSTM step =======================
// Launch t = 0..L_ (inclusive), grid 256: blocks 0..127 = layer0 step t,
// blocks 128..255 = layer1 step t-1. No grid sync: kernel boundary orders
// h0(t-1) (written by previous launch) before layer1 reads it.
// Block owns hidden units j = blk*4..blk*4+3, all 4 gates, all 8 batches.
// h layout: [t][b][c] (t-major). pre0 layout: [(t*8+b)][2048] incl. both biases.
// Layer1 computes Wih1@h0(t-1) + bih1 + bhh1 + Whh1@h1(t-2) in-kernel.
__global__ __launch_bounds__(256, 1) void lstm_step_fused(
    const float* __restrict__ pre0,
    const float* __restrict__ Whh0,
    const float* __restrict__ Wih1,
    const float* __restrict__ Whh1,
    const float* __restrict__ bih1,
    const float* __restrict__ bhh1,
    float* __restrict__ h0seq,
    float* __restrict__ h1seq,
    float* __restrict__ c0st, float* __restrict__ c1st,
    int t)
{
    int layer = blockIdx.x >> 7;
    int blk = blockIdx.x & 127;
    if (layer == 0 && t >= L_) return;
    if (layer == 1 && t == 0) return;
    int tt = layer ? (t - 1) : t;

    __shared__ float hA[512][12];   // recurrent h(tt-1), transposed [c][b]
    __shared__ float hB[512][12];   // layer1 only: h0(tt)
    __shared__ float red[4][8][16];
    __shared__ float gates[4][4][8];

    int tid = threadIdx.x;
    int csplit = tid >> 3;             // 0..31: which c residue
    int rowg   = (tid >> 1) & 3;       // hidden jj this thread computes
    int bg     = tid & 1;              // batch half (4 batches)

    float* hout = layer ? h1seq : h0seq;
    float* cst  = layer ? c1st  : c0st;

    // ---- stage recurrent h(tt-1) ----
    if (tt == 0) {
        for (int idx = tid; idx < 4096; idx += 256)
            hA[idx & 511][idx >> 9] = 0.f;
    } else {
        const float* src = (layer ? h1seq : h0seq) + (size_t)(tt - 1) * 4096;
        for (int idx = tid; idx < 4096; idx += 256) {
            int b = idx >> 9, c = idx & 511;
            hA[c][b] = src[idx];
        }
    }
    // ---- layer1: stage h0(tt) ----
    if (layer) {
        const float* src = h0seq + (size_t)tt * 4096;
        for (int idx = tid; idx < 4096; idx += 256) {
            int b = idx >> 9, c = idx & 511;
            hB[c][b] = src[idx];
        }
    }

    // ---- register weights: wA = recurrent, wB = layer1 input-side ----
    int row = blk * 4 + rowg;
    float4 wA[16], wB[16];
    {
        const float* wb = (layer ? Whh1 : Whh0) + (size_t)row * 512 + csplit;
#pragma unroll
        for (int cc = 0; cc < 16; ++cc) {
            int c32 = cc * 32;
            wA[cc].x = wb[c32];
            wA[cc].y = wb[c32 + 262144];
            wA[cc].z = wb[c32 + 524288];
            wA[cc].w = wb[c32 + 786432];
        }
    }
    if (layer) {
        const float* wb = Wih1 + (size_t)row * 512 + csplit;
#pragma unroll
        for (int cc = 0; cc < 16; ++cc) {
            int c32 = cc * 32;
            wB[cc].x = wb[c32];
            wB[cc].y = wb[c32 + 262144];
            wB[cc].z = wb[c32 + 524288];
            wB[cc].w = wb[c32 + 786432];
        }
    }

    int f_jj = tid >> 5, f_g = (tid >> 3) & 3, f_b = tid & 7;
    float mypre = 0.f;
    if (tid < 128) {
        int grow = f_g * 512 + blk * 4 + f_jj;
        mypre = layer ? (bih1[grow] + bhh1[grow])
                      : pre0[((size_t)(tt * 8 + f_b)) * 2048 + grow];
    }
    __syncthreads();

    // ---- matvec partials: acc[g][b4] over this thread's 16 c values ----
    float acc[4][4] = {{0.f,0.f,0.f,0.f},{0.f,0.f,0.f,0.f},{0.f,0.f,0.f,0.f},{0.f,0.f,0.f,0.f}};
#pragma unroll
    for (int cc = 0; cc < 16; ++cc) {
        int c = csplit + 32 * cc;
        float4 hv = *(const float4*)&hA[c][bg * 4];
        float hb[4] = {hv.x, hv.y, hv.z, hv.w};
        float wg[4] = {wA[cc].x, wA[cc].y, wA[cc].z, wA[cc].w};
#pragma unroll
        for (int g = 0; g < 4; ++g)
#pragma unroll
            for (int b4 = 0; b4 < 4; ++b4)
                acc[g][b4] = fmaf(wg[g], hb[b4], acc[g][b4]);
    }
    if (layer) {
#pragma unroll
        for (int cc = 0; cc < 16; ++cc) {
            int c = csplit + 32 * cc;
            float4 hv = *(const float4*)&hB[c][bg * 4];
            float hb[4] = {hv.x, hv.y, hv.z, hv.w};
            float wg[4] = {wB[cc].x, wB[cc].y, wB[cc].z, wB[cc].w};
#pragma unroll
            for (int g = 0; g < 4; ++g)
#pragma unroll
                for (int b4 = 0; b4 < 4; ++b4)
                    acc[g][b4] = fmaf(wg[g], hb[b4], acc[g][b4]);
        }
    }

    // ---- reduce over csplit: intra-wave (lane bits 3..5 == csplit bits 0..2) ----
#pragma unroll
    for (int m = 8; m <= 32; m <<= 1)
#pragma unroll
        for (int g = 0; g < 4; ++g)
#pragma unroll
            for (int b4 = 0; b4 < 4; ++b4)
                acc[g][b4] += __shfl_xor(acc[g][b4], m);
    int lane = tid & 63;
    if (lane < 8) {
        int w = tid >> 6;
#pragma unroll
        for (int g = 0; g < 4; ++g)
#pragma unroll
            for (int b4 = 0; b4 < 4; ++b4)
                red[w][lane][g * 4 + b4] = acc[g][b4];
    }
    __syncthreads();

    // ---- cross-wave sum + x-side ----
    if (tid < 128) {
        int gidx = f_jj * 2 + (f_b >> 2);
        int vi = f_g * 4 + (f_b & 3);
        gates[f_jj][f_g][f_b] = red[0][gidx][vi] + red[1][gidx][vi]
                              + red[2][gidx][vi] + red[3][gidx][vi] + mypre;
    }
    __syncthreads();

    // ---- gate math + writes ----
    if (tid < 32) {
        int jj = tid >> 3, b = tid & 7;
        float gi = gates[jj][0][b], gf = gates[jj][1][b];
        float gg = gates[jj][2][b], go = gates[jj][3][b];
        int ci = b * 512 + blk * 4 + jj;
        float cprev = (tt == 0) ? 0.f : cst[ci];
        float si = 1.f / (1.f + expf(-gi));
        float sf = 1.f / (1.f + expf(-gf));
        float so = 1.f / (1.f + expf(-go));
        float cn = sf * cprev + si * tanhf(gg);
        cst[ci] = cn;
        hout[((size_t)tt * 8 + b) * 512 + blk * 4 + jj] = so * tanhf(cn);
    }
}

// ======================= h1 [t][b][c] -> [b*L+t][c] =======================
__global__ __launch_bounds__(256) void transpose_h(const float* __restrict__ h1,
                                                   float* __restrict__ h1m)
{
    int idx = blockIdx.x * 256 + threadIdx.x;
    if (idx >= M_ * 512) return;
    int c = idx & 511;
    int m = idx >> 9;            // = t*8+b
    int tq = m >> 3, b = m & 7;
    h1m[((size_t)(b * L_ + tq)) * 512 + c] = h1[idx];
}

// ======================= banded attention (radius 50) =======================
__global__ __launch_bounds__(128) void attn_kernel(const float* __restrict__ q,
                                                   const float* __restrict__ k,
                                                   const float* __restrict__ cnt,
                                                   const float* __restrict__ rel,
                                                   float* __restrict__ out)
{
    int t = blockIdx.x, h = blockIdx.y, b = blockIdx.z;
    int s_lo = max(0, t - R_), s_hi = min(L_ - 1, t + R_);
    int W = s_hi - s_lo + 1;
    int tid = threadIdx.x;

    __shared__ float qrow[64];
    __shared__ float dots[104];
    __shared__ float red[128];

    const float* qp = q + ((size_t)(b * L_ + t) * C_ + h * D_);
    if (tid < 64) qrow[tid] = qp[tid];
    __syncthreads();

    if (tid < W) {
        int s = s_lo + tid;
        const float* kp = k + ((size_t)(b * L_ + s) * C_ + h * D_);
        const float* rp = rel + (R_ + t - s) * D_;
        float acc = 0.f;
#pragma unroll 8
        for (int d = 0; d < 64; ++d)
            acc += qrow[d] * (kp[d] + 0.3f * rp[d]);
        dots[tid] = acc;
    }
    __syncthreads();

    red[tid] = (tid < W) ? dots[tid] : -INFINITY;
    __syncthreads();
    for (int s = 64; s > 0; s >>= 1) {
        if (tid < s) red[tid] = fmaxf(red[tid], red[tid + s]);
        __syncthreads();
    }
    float mx = red[0];
    __syncthreads();
    float e = 0.f;
    if (tid < W) { e = expf(dots[tid] - mx); dots[tid] = e; }
    red[tid] = e;
    __syncthreads();
    for (int s = 64; s > 0; s >>= 1) {
        if (tid < s) red[tid] += red[tid + s];
        __syncthreads();
    }
    float inv = 1.f / red[0];
    if (tid < W) dots[tid] *= inv;
    __syncthreads();

    if (tid < 64) {
        float acc = 0.f;
        const float* cb = cnt + ((size_t)(b * L_ + s_lo) * C_ + h * D_ + tid);
        const float* rb = rel + (R_ + t - s_lo) * D_ + tid;
        for (int i = 0; i < W; ++i)
            acc += dots[i] * (cb[(size_t)i * C_] + 0.3f * rb[-i * D_]);
        out[(size_t)(b * L_ + t) * C_ + h * D_ + tid] = acc;
    }
}

// ======================= BatchNorm training stats =======================
__global__ __launch_bounds__(256) void bn_stats(const float* __restrict__ fcout, float* __restrict__ stats)
{
    int o = blockIdx.x;
    int tid = threadIdx.x;
    float s = 0.f, ss = 0.f;
    for (int m = tid; m < M_; m += 256) {
        float v = fcout[(size_t)m * 512 + o];
        s += v; ss += v * v;
    }
    __shared__ float rs[256], rq[256];
    rs[tid] = s; rq[tid] = ss;
    __syncthreads();
    for (int k = 128; k > 0; k >>= 1) {
        if (tid < k) { rs[tid] += rs[tid + k]; rq[tid] += rq[tid + k]; }
        __syncthreads();
    }
    if (tid == 0) {
        float mean = rs[0] / (float)M_;
        float var = rq[0] / (float)M_ - mean * mean;
        stats[o] = mean;
        stats[512 + o] = rsqrtf(fmaxf(var, 0.f) + 1e-5f);
    }
}

// ======================= BN apply + ReLU + scale + residual =======================
__global__ __launch_bounds__(256) void bn_apply(const float* __restrict__ fcout,
                                                const float* __restrict__ stats,
                                                const float* __restrict__ bng, const float* __restrict__ bnb,
                                                const float* __restrict__ ascl,
                                                float* __restrict__ xres)
{
    int idx = blockIdx.x * 256 + threadIdx.x;
    if (idx >= M_ * 512) return;
    int c = idx & 511;
    float v = (fcout[idx] - stats[c]) * stats[512 + c] * bng[c] + bnb[c];
    v = fmaxf(v, 0.f) * ascl[c];
    xres[idx] += v;
}

// ======================= host launch =======================
extern "C" void kernel_launch(void* const* d_in, const int* in_sizes, int n_in,
                              void* d_out, int out_size, void* d_ws, size_t ws_size,
                              hipStream_t stream)
{
    const float* meg  = (const float*)d_in[0];
    const float* w1   = (const float*)d_in[1];
    const float* b1   = (const float*)d_in[2];
    const float* w2   = (const float*)d_in[3];
    const float* b2   = (const float*)d_in[4];
    const float* semb = (const float*)d_in[5];
    const float* Wih0 = (const float*)d_in[6];
    const float* Whh0 = (const float*)d_in[7];
    const float* bih0 = (const float*)d_in[8];
    const float* bhh0 = (const float*)d_in[9];
    const float* Wih1 = (const float*)d_in[10];
    const float* Whh1 = (const float*)d_in[11];
    const float* bih1 = (const float*)d_in[12];
    const float* bhh1 = (const float*)d_in[13];
    const float* qw   = (const float*)d_in[14];
    const float* qb   = (const float*)d_in[15];
    const float* kw   = (const float*)d_in[16];
    const float* kb   = (const float*)d_in[17];
    const float* cw   = (const float*)d_in[18];
    const float* cbi  = (const float*)d_in[19];
    const float* rel  = (const float*)d_in[20];
    const float* fcw  = (const float*)d_in[21];
    const float* fcb  = (const float*)d_in[22];
    const float* bng  = (const float*)d_in[23];
    const float* bnb  = (const float*)d_in[24];
    const float* ascl = (const float*)d_in[25];
    const float* outw = (const float*)d_in[26];
    const float* outb = (const float*)d_in[27];
    const int* subj = (const int*)d_in[28];
    float* out = (float*)d_out;

    float* ws = (float*)d_ws;
    // arena (float offsets) — max 21,271,040 floats (same footprint as round 2)
    float* c0    = ws + 0;          // [8][512] cell state L0 (LSTM phase; x1 region dead then)
    float* c1    = ws + 4096;       // [8][512] cell state L1
    float* x1    = ws + 0;          // [8200][512] conv phase      -> 4,198,400
    float* x2bt  = ws + 4198400;    // [4104][576]                 -> 6,562,304
    float* pre0  = ws + 6562304;    // [(t*8+b)][2048]             -> 14,967,296
    float* h0    = ws + 14967296;   // [t][b][c]                   -> 17,068,544
    float* h1    = ws + 17068544;   // [t][b][c]                   -> 19,169,792
    float* h1m   = ws + 19169792;   // [b*L+t][c]                  -> 21,271,040
    // post-LSTM overlays (conv/LSTM buffers dead):
    float* qb_f  = ws + 0;          // q  [4104][512] over x1/c0/c1
    float* kb_f  = ws + 2101248;    // k
    float* cb_f  = ws + 4202496;    // cnt (spills into dead x2bt region)
    float* attno = ws + 6562304;    // over pre0
    float* fco   = ws + 8663552;
    float* stats = ws + 10764800;   // 1024 floats

    auto gemm = [&](const void* A, const float* Bw, const float* bi1, const float* bi2,
                    float* Cf, int Msz, int Nsz, int Ksz,
                    int lda, int ldc, int amode, int cmode, int relu) {
        dim3 g((Msz + 63) / 64, Nsz / 64);
        gemm_kernel<<<g, 256, 0, stream>>>(A, Bw, bi1, bi2, Cf,
                                           Msz, Nsz, Ksz, lda, ldc, amode, cmode, relu);
    };

    // conv1 (im2col from meg) -> x1 [b*1025+t][512], relu
    gemm(meg, w1, b1, nullptr, x1, M1_, 512, K1_, 0, 512, 2, 0, 1);
    // conv2 (im2col from x1) -> x2bt [b*513+t][576] cols 0..511, relu
    gemm(x1, w2, b2, nullptr, x2bt, M_, 512, 2048, 0, CE_, 3, 0, 1);
    // subject embedding -> cols 512..575
    emb_kernel<<<(M_ * 64 + 255) / 256, 256, 0, stream>>>(semb, subj, x2bt);

    // layer-0 x-projection (time-major output, both biases folded)
    gemm(x2bt, Wih0, bih0, bhh0, pre0, M_, 2048, CE_, CE_, 2048, 0, 2, 0);

    // fused 2-layer LSTM: layer0 step t + layer1 step t-1 per launch
    for (int t = 0; t <= L_; ++t)
        lstm_step_fused<<<256, 256, 0, stream>>>(pre0, Whh0, Wih1, Whh1, bih1, bhh1,
                                                 h0, h1, c0, c1, t);

    // h1 -> batch-major
    transpose_h<<<(M_ * 512 + 255) / 256, 256, 0, stream>>>(h1, h1m);

    // attention projections
    gemm(h1m, qw, qb, nullptr, qb_f, M_, 512, 512, 512, 512, 0, 0, 0);
    gemm(h1m, kw, kb, nullptr, kb_f, M_, 512, 512, 512, 512, 0, 0, 0);
    gemm(h1m, cw, cbi, nullptr, cb_f, M_, 512, 512, 512, 512, 0, 0, 0);

    attn_kernel<<<dim3(L_, H_, B_), 128, 0, stream>>>(qb_f, kb_f, cb_f, rel, attno);

    // fc + BN(train) + relu*scale + residual into h1m
    gemm(attno, fcw, fcb, nullptr, fco, M_, 512, 512, 512, 512, 0, 0, 0);
    bn_stats<<<512, 256, 0, stream>>>(fco, stats);
    bn_apply<<<(M_ * 512 + 255) / 256, 256, 0, stream>>>(fco, stats, bng, bnb, ascl, h1m);

    // final projection -> d_out [b][128][t] fp32
    gemm(h1m, outw, outb, nullptr, out, M_, 128, 512, 512, 0, 0, 1, 0);
}

// Round 5
// 5858.155 us; speedup vs baseline: 3.2534x; 1.5249x over previous
//
#include <hip/hip_runtime.h>
#include <cstdint>
#include <cmath>

typedef unsigned short u16;
typedef unsigned int u32;

// ---- model dims ----
#define B_    8
#define T_IN  2048
#define CIN1  273
#define L1_   1025
#define L_    513
#define C_    512
#define CE_   576
#define M1_   (B_*L1_)   /* 8200 */
#define M_    (B_*L_)    /* 4104 */
#define K1_   (CIN1*4)   /* 1092 */
#define H_    8
#define D_    64
#define R_    50

// ======================= generic GEMM: C[m,n] = sum_k A[m,k]*B[n,k] + bias =======================
// amode: 0 = fp32 row-major A (lda), 2 = conv1 im2col from meg, 3 = conv2 im2col from x1
// cmode: 0 = C[m*ldc+n]; 1 = out[b][n][t] (n<128); 2 = C[(t*8+b)*ldc+n] (time-major)
__device__ __forceinline__ float a_load(const void* A, int m, int k, int lda, int amode) {
    if (amode == 0) {
        return ((const float*)A)[(size_t)m * lda + k];
    } else if (amode == 2) {
        int b = m / L1_, t = m - b * L1_;
        int ci = k >> 2, kk = k & 3;
        int it = 2 * t - 2 + kk;
        if ((unsigned)it >= (unsigned)T_IN) return 0.f;
        return ((const float*)A)[((size_t)(b * CIN1 + ci)) * T_IN + it];
    } else {
        int b = m / L_, t = m - b * L_;
        int ci = k >> 2, kk = k & 3;
        int it = 2 * t - 2 + kk;
        if ((unsigned)it >= (unsigned)L1_) return 0.f;
        return ((const float*)A)[((size_t)(b * L1_ + it)) * C_ + ci];
    }
}

__global__ __launch_bounds__(256) void gemm_kernel(
    const void* __restrict__ Aptr, const float* __restrict__ Bptr,
    const float* __restrict__ bias1, const float* __restrict__ bias2,
    float* __restrict__ Cf,
    int Msz, int Nsz, int Ksz, int lda, int ldc, int amode, int cmode, int relu)
{
    __shared__ float As[16][68];
    __shared__ float Bs[16][68];
    int tid = threadIdx.x;
    int tx = tid & 15, ty = tid >> 4;
    int kq = tid & 15, mq = tid >> 4;
    int m0 = blockIdx.x * 64, n0 = blockIdx.y * 64;

    float acc[4][4];
#pragma unroll
    for (int i = 0; i < 4; ++i)
#pragma unroll
        for (int j = 0; j < 4; ++j) acc[i][j] = 0.f;

    for (int k0 = 0; k0 < Ksz; k0 += 16) {
        int k = k0 + kq;
#pragma unroll
        for (int j = 0; j < 4; ++j) {
            int rl = mq + 16 * j;
            int m = m0 + rl;
            float av = 0.f;
            if (m < Msz && k < Ksz) av = a_load(Aptr, m, k, lda, amode);
            As[kq][rl] = av;
            float bv = 0.f;
            if (k < Ksz) bv = Bptr[(size_t)(n0 + rl) * Ksz + k];
            Bs[kq][rl] = bv;
        }
        __syncthreads();
#pragma unroll
        for (int kk = 0; kk < 16; ++kk) {
            float a4[4], b4[4];
            *(float4*)a4 = *(const float4*)&As[kk][ty * 4];
            *(float4*)b4 = *(const float4*)&Bs[kk][tx * 4];
#pragma unroll
            for (int i = 0; i < 4; ++i)
#pragma unroll
                for (int j = 0; j < 4; ++j) acc[i][j] += a4[i] * b4[j];
        }
        __syncthreads();
    }

#pragma unroll
    for (int i = 0; i < 4; ++i) {
        int m = m0 + ty * 4 + i;
        if (m >= Msz) continue;
#pragma unroll
        for (int j = 0; j < 4; ++j) {
            int n = n0 + tx * 4 + j;
            float v = acc[i][j] + bias1[n] + (bias2 ? bias2[n] : 0.f);
            if (relu) v = fmaxf(v, 0.f);
            if (cmode == 0) {
                Cf[(size_t)m * ldc + n] = v;
            } else if (cmode == 1) {
                int b = m / L_, t = m - b * L_;
                Cf[((size_t)(b * 128 + n)) * L_ + t] = v;
            } else {
                int b = m / L_, t = m - b * L_;
                Cf[((size_t)(t * 8 + b)) * ldc + n] = v;
            }
        }
    }
}

// ======================= subject embedding concat =======================
__global__ __launch_bounds__(256) void emb_kernel(const float* __restrict__ semb,
                                                  const int* __restrict__ subj,
                                                  float* __restrict__ x2bt)
{
    int idx = blockIdx.x * 256 + threadIdx.x;
    if (idx >= M_ * 64) return;
    int m = idx >> 6, e = idx & 63;
    int b = m / L_;
    x2bt[(size_t)m * CE_ + 512 + e] = semb[subj[b] * 64 + e];
}

// ======================= weight pack: fp32 [2048][512] -> bf16x2 u32, layout [j][g][i][c2] =======================
// word gid: c2 = gid&63, i = (gid>>6)&3, g = (gid>>8)&3, j = gid>>10.
// holds (W[g*512+j][2*(c2+64i)], W[g*512+j][2*(c2+64i)+1]) as (lo,hi) bf16 RNE.
__device__ __forceinline__ u32 f2bf_rne(float f) {
    u32 x = __float_as_uint(f);
    return (x + 0x7fffu + ((x >> 16) & 1u)) >> 16;
}
__global__ __launch_bounds__(256) void pack_w(const float* __restrict__ W, u32* __restrict__ P)
{
    int gid = blockIdx.x * 256 + threadIdx.x;   // 524288 total
    int c2 = gid & 63, i = (gid >> 6) & 3, g = (gid >> 8) & 3, j = gid >> 10;
    int row = g * 512 + j;
    int c0 = 2 * (c2 + 64 * i);
    u32 lo = f2bf_rne(W[(size_t)row * 512 + c0]);
    u32 hi = f2bf_rne(W[(size_t)row * 512 + c0 + 1]);
    P[gid] = lo | (hi << 16);
}

// ======================= fused 2-layer LSTM step (streaming bf16 weights) =======================
// Launch t = 0..L_: blocks 0..127 = layer0 step t, blocks 128..255 = layer1 step t-1.
// Wave rg owns hidden unit j = blk*4+rg (all 4 gates, all 8 batches); lane = c-pair slot.
// h layout [t][b][c]. pre0[(t*8+b)*2048 + g*512+j] has x@Wih0 + bih0 + bhh0.
__global__ __launch_bounds__(256, 1) void lstm_step_fused(
    const float* __restrict__ pre0,
    const u32* __restrict__ P0,    // Whh0 packed
    const u32* __restrict__ P1,    // Wih1 packed
    const u32* __restrict__ P2,    // Whh1 packed
    const float* __restrict__ bih1,
    const float* __restrict__ bhh1,
    float* __restrict__ h0seq,
    float* __restrict__ h1seq,
    float* __restrict__ c0st, float* __restrict__ c1st,
    int t)
{
    int layer = blockIdx.x >> 7;
    int blk = blockIdx.x & 127;
    if (layer == 0 && t >= L_) return;
    if (layer == 1 && t == 0) return;
    int tt = layer ? (t - 1) : t;

    int tid = threadIdx.x;
    int c2 = tid & 63;         // lane = c-pair slot
    int rg = tid >> 6;         // wave = hidden-unit offset
    int j = blk * 4 + rg;

    __shared__ float part[4 * 8 * 33];    // [rg*8+p][x=g*8+b], stride 33
    __shared__ float gates[4 * 33];       // [rg][x], stride 33

    float acc[4][8];
#pragma unroll
    for (int g = 0; g < 4; ++g)
#pragma unroll
        for (int b = 0; b < 8; ++b) acc[g][b] = 0.f;

    // ---- recurrent matvec: stream weights, h direct from global (coalesced, L1-shared) ----
    const float* hAbase = (layer ? h1seq : h0seq) + (size_t)(tt - 1) * 4096;
    const u32* wA = (layer ? P2 : P0) + (size_t)j * 1024 + c2;
    if (tt > 0) {
#pragma unroll
        for (int i = 0; i < 4; ++i) {
            float2 hv[8];
#pragma unroll
            for (int b = 0; b < 8; ++b)
                hv[b] = *(const float2*)&hAbase[b * 512 + 2 * (c2 + 64 * i)];
#pragma unroll
            for (int g = 0; g < 4; ++g) {
                u32 w = wA[g * 256 + i * 64];
                float w0 = __uint_as_float(w << 16);
                float w1 = __uint_as_float(w & 0xffff0000u);
#pragma unroll
                for (int b = 0; b < 8; ++b)
                    acc[g][b] = fmaf(w0, hv[b].x, fmaf(w1, hv[b].y, acc[g][b]));
            }
        }
    }
    // ---- layer1 input-side matvec: Wih1 @ h0(tt) ----
    if (layer) {
        const float* hBbase = h0seq + (size_t)tt * 4096;
        const u32* wB = P1 + (size_t)j * 1024 + c2;
#pragma unroll
        for (int i = 0; i < 4; ++i) {
            float2 hv[8];
#pragma unroll
            for (int b = 0; b < 8; ++b)
                hv[b] = *(const float2*)&hBbase[b * 512 + 2 * (c2 + 64 * i)];
#pragma unroll
            for (int g = 0; g < 4; ++g) {
                u32 w = wB[g * 256 + i * 64];
                float w0 = __uint_as_float(w << 16);
                float w1 = __uint_as_float(w & 0xffff0000u);
#pragma unroll
                for (int b = 0; b < 8; ++b)
                    acc[g][b] = fmaf(w0, hv[b].x, fmaf(w1, hv[b].y, acc[g][b]));
            }
        }
    }

    // ---- reduce over c2: 3-level butterfly (bits 3..5), then lanes 0..7 hold partials ----
#pragma unroll
    for (int m = 8; m <= 32; m <<= 1)
#pragma unroll
        for (int g = 0; g < 4; ++g)
#pragma unroll
            for (int b = 0; b < 8; ++b)
                acc[g][b] += __shfl_xor(acc[g][b], m);
    if (c2 < 8) {
#pragma unroll
        for (int g = 0; g < 4; ++g)
#pragma unroll
            for (int b = 0; b < 8; ++b)
                part[(rg * 8 + c2) * 33 + g * 8 + b] = acc[g][b];
    }
    __syncthreads();

    // ---- sum 8 partials + x-side, store gates ----
    if (tid < 128) {
        int w = tid >> 5, x = tid & 31;
        int g = x >> 3, b = x & 7;
        float s = 0.f;
#pragma unroll
        for (int p = 0; p < 8; ++p) s += part[(w * 8 + p) * 33 + x];
        int grow = g * 512 + blk * 4 + w;
        s += layer ? (bih1[grow] + bhh1[grow])
                   : pre0[((size_t)(tt * 8 + b)) * 2048 + grow];
        gates[w * 33 + x] = s;
    }
    __syncthreads();

    // ---- gate math + writes ----
    if (tid < 32) {
        int w = tid >> 3, b = tid & 7;
        float gi = gates[w * 33 + 0 * 8 + b];
        float gf = gates[w * 33 + 1 * 8 + b];
        float gg = gates[w * 33 + 2 * 8 + b];
        float go = gates[w * 33 + 3 * 8 + b];
        float* cst = layer ? c1st : c0st;
        int ji = blk * 4 + w;
        int ci = b * 512 + ji;
        float cprev = (tt == 0) ? 0.f : cst[ci];
        float si = 1.f / (1.f + expf(-gi));
        float sf = 1.f / (1.f + expf(-gf));
        float so = 1.f / (1.f + expf(-go));
        float cn = sf * cprev + si * tanhf(gg);
        cst[ci] = cn;
        float* hout = layer ? h1seq : h0seq;
        hout[((size_t)tt * 8 + b) * 512 + ji] = so * tanhf(cn);
    }
}

// ======================= h1 [t][b][c] -> [b*L+t][c] =======================
__global__ __launch_bounds__(256) void transpose_h(const float* __restrict__ h1,
                                                   float* __restrict__ h1m)
{
    int idx = blockIdx.x * 256 + threadIdx.x;
    if (idx >= M_ * 512) return;
    int c = idx & 511;
    int m = idx >> 9;            // = t*8+b
    int tq = m >> 3, b = m & 7;
    h1m[((size_t)(b * L_ + tq)) * 512 + c] = h1[idx];
}

// ======================= banded attention (radius 50) =======================
__global__ __launch_bounds__(128) void attn_kernel(const float* __restrict__ q,
                                                   const float* __restrict__ k,
                                                   const float* __restrict__ cnt,
                                                   const float* __restrict__ rel,
                                                   float* __restrict__ out)
{
    int t = blockIdx.x, h = blockIdx.y, b = blockIdx.z;
    int s_lo = max(0, t - R_), s_hi = min(L_ - 1, t + R_);
    int W = s_hi - s_lo + 1;
    int tid = threadIdx.x;

    __shared__ float qrow[64];
    __shared__ float dots[104];
    __shared__ float red[128];

    const float* qp = q + ((size_t)(b * L_ + t) * C_ + h * D_);
    if (tid < 64) qrow[tid] = qp[tid];
    __syncthreads();

    if (tid < W) {
        int s = s_lo + tid;
        const float* kp = k + ((size_t)(b * L_ + s) * C_ + h * D_);
        const float* rp = rel + (R_ + t - s) * D_;
        float acc = 0.f;
#pragma unroll 8
        for (int d = 0; d < 64; ++d)
            acc += qrow[d] * (kp[d] + 0.3f * rp[d]);
        dots[tid] = acc;
    }
    __syncthreads();

    red[tid] = (tid < W) ? dots[tid] : -INFINITY;
    __syncthreads();
    for (int s = 64; s > 0; s >>= 1) {
        if (tid < s) red[tid] = fmaxf(red[tid], red[tid + s]);
        __syncthreads();
    }
    float mx = red[0];
    __syncthreads();
    float e = 0.f;
    if (tid < W) { e = expf(dots[tid] - mx); dots[tid] = e; }
    red[tid] = e;
    __syncthreads();
    for (int s = 64; s > 0; s >>= 1) {
        if (tid < s) red[tid] += red[tid + s];
        __syncthreads();
    }
    float inv = 1.f / red[0];
    if (tid < W) dots[tid] *= inv;
    __syncthreads();

    if (tid < 64) {
        float acc = 0.f;
        const float* cb = cnt + ((size_t)(b * L_ + s_lo) * C_ + h * D_ + tid);
        const float* rb = rel + (R_ + t - s_lo) * D_ + tid;
        for (int i = 0; i < W; ++i)
            acc += dots[i] * (cb[(size_t)i * C_] + 0.3f * rb[-i * D_]);
        out[(size_t)(b * L_ + t) * C_ + h * D_ + tid] = acc;
    }
}

// ======================= BatchNorm training stats =======================
__global__ __launch_bounds__(256) void bn_stats(const float* __restrict__ fcout, float* __restrict__ stats)
{
    int o = blockIdx.x;
    int tid = threadIdx.x;
    float s = 0.f, ss = 0.f;
    for (int m = tid; m < M_; m += 256) {
        float v = fcout[(size_t)m * 512 + o];
        s += v; ss += v * v;
    }
    __shared__ float rs[256], rq[256];
    rs[tid] = s; rq[tid] = ss;
    __syncthreads();
    for (int k = 128; k > 0; k >>= 1) {
        if (tid < k) { rs[tid] += rs[tid + k]; rq[tid] += rq[tid + k]; }
        __syncthreads();
    }
    if (tid == 0) {
        float mean = rs[0] / (float)M_;
        float var = rq[0] / (float)M_ - mean * mean;
        stats[o] = mean;
        stats[512 + o] = rsqrtf(fmaxf(var, 0.f) + 1e-5f);
    }
}

// ======================= BN apply + ReLU + scale + residual =======================
__global__ __launch_bounds__(256) void bn_apply(const float* __restrict__ fcout,
                                                const float* __restrict__ stats,
                                                const float* __restrict__ bng, const float* __restrict__ bnb,
                                                const float* __restrict__ ascl,
                                                float* __restrict__ xres)
{
    int idx = blockIdx.x * 256 + threadIdx.x;
    if (idx >= M_ * 512) return;
    int c = idx & 511;
    float v = (fcout[idx] - stats[c]) * stats[512 + c] * bng[c] + bnb[c];
    v = fmaxf(v, 0.f) * ascl[c];
    xres[idx] += v;
}

// ======================= host launch =======================
extern "C" void kernel_launch(void* const* d_in, const int* in_sizes, int n_in,
                              void* d_out, int out_size, void* d_ws, size_t ws_size,
                              hipStream_t stream)
{
    const float* meg  = (const float*)d_in[0];
    const float* w1   = (const float*)d_in[1];
    const float* b1   = (const float*)d_in[2];
    const float* w2   = (const float*)d_in[3];
    const float* b2   = (const float*)d_in[4];
    const float* semb = (const float*)d_in[5];
    const float* Wih0 = (const float*)d_in[6];
    const float* Whh0 = (const float*)d_in[7];
    const float* bih0 = (const float*)d_in[8];
    const float* bhh0 = (const float*)d_in[9];
    const float* Wih1 = (const float*)d_in[10];
    const float* Whh1 = (const float*)d_in[11];
    const float* bih1 = (const float*)d_in[12];
    const float* bhh1 = (const float*)d_in[13];
    const float* qw   = (const float*)d_in[14];
    const float* qb   = (const float*)d_in[15];
    const float* kw   = (const float*)d_in[16];
    const float* kb   = (const float*)d_in[17];
    const float* cw   = (const float*)d_in[18];
    const float* cbi  = (const float*)d_in[19];
    const float* rel  = (const float*)d_in[20];
    const float* fcw  = (const float*)d_in[21];
    const float* fcb  = (const float*)d_in[22];
    const float* bng  = (const float*)d_in[23];
    const float* bnb  = (const float*)d_in[24];
    const float* ascl = (const float*)d_in[25];
    const float* outw = (const float*)d_in[26];
    const float* outb = (const float*)d_in[27];
    const int* subj = (const int*)d_in[28];
    float* out = (float*)d_out;

    float* ws = (float*)d_ws;
    // arena (float offsets) — max 21,271,040 floats
    float* x1    = ws + 0;          // [8200][512] conv phase only -> 4,198,400
    // LSTM-phase overlays of the dead x1 region:
    u32*   P0    = (u32*)(ws + 0);        // Whh0 bf16 packed: 524,288 words
    u32*   P1    = (u32*)(ws + 524288);   // Wih1
    u32*   P2    = (u32*)(ws + 1048576);  // Whh1
    float* c0    = ws + 1572864;    // [8][512] cell state L0
    float* c1    = ws + 1576960;    // [8][512] cell state L1
    float* x2bt  = ws + 4198400;    // [4104][576]                 -> 6,562,304
    float* pre0  = ws + 6562304;    // [(t*8+b)][2048]             -> 14,967,296
    float* h0    = ws + 14967296;   // [t][b][c]                   -> 17,068,544
    float* h1    = ws + 17068544;   // [t][b][c]                   -> 19,169,792
    float* h1m   = ws + 19169792;   // [b*L+t][c]                  -> 21,271,040
    // post-LSTM overlays:
    float* qb_f  = ws + 0;          // q  [4104][512]
    float* kb_f  = ws + 2101248;    // k
    float* cb_f  = ws + 4202496;    // cnt (spills into dead x2bt region)
    float* attno = ws + 6562304;    // over pre0
    float* fco   = ws + 8663552;
    float* stats = ws + 10764800;   // 1024 floats

    auto gemm = [&](const void* A, const float* Bw, const float* bi1, const float* bi2,
                    float* Cf, int Msz, int Nsz, int Ksz,
                    int lda, int ldc, int amode, int cmode, int relu) {
        dim3 g((Msz + 63) / 64, Nsz / 64);
        gemm_kernel<<<g, 256, 0, stream>>>(A, Bw, bi1, bi2, Cf,
                                           Msz, Nsz, Ksz, lda, ldc, amode, cmode, relu);
    };

    // conv1 (im2col from meg) -> x1 [b*1025+t][512], relu
    gemm(meg, w1, b1, nullptr, x1, M1_, 512, K1_, 0, 512, 2, 0, 1);
    // conv2 (im2col from x1) -> x2bt [b*513+t][576] cols 0..511, relu
    gemm(x1, w2, b2, nullptr, x2bt, M_, 512, 2048, 0, CE_, 3, 0, 1);
    // subject embedding -> cols 512..575
    emb_kernel<<<(M_ * 64 + 255) / 256, 256, 0, stream>>>(semb, subj, x2bt);

    // pack LSTM weights to bf16 (x1 region is dead now)
    pack_w<<<2048, 256, 0, stream>>>(Whh0, P0);
    pack_w<<<2048, 256, 0, stream>>>(Wih1, P1);
    pack_w<<<2048, 256, 0, stream>>>(Whh1, P2);

    // layer-0 x-projection (time-major output, both biases folded)
    gemm(x2bt, Wih0, bih0, bhh0, pre0, M_, 2048, CE_, CE_, 2048, 0, 2, 0);

    // fused 2-layer LSTM: layer0 step t + layer1 step t-1 per launch
    for (int t = 0; t <= L_; ++t)
        lstm_step_fused<<<256, 256, 0, stream>>>(pre0, P0, P1, P2, bih1, bhh1,
                                                 h0, h1, c0, c1, t);

    // h1 -> batch-major
    transpose_h<<<(M_ * 512 + 255) / 256, 256, 0, stream>>>(h1, h1m);

    // attention projections
    gemm(h1m, qw, qb, nullptr, qb_f, M_, 512, 512, 512, 512, 0, 0, 0);
    gemm(h1m, kw, kb, nullptr, kb_f, M_, 512, 512, 512, 512, 0, 0, 0);
    gemm(h1m, cw, cbi, nullptr, cb_f, M_, 512, 512, 512, 512, 0, 0, 0);

    attn_kernel<<<dim3(L_, H_, B_), 128, 0, stream>>>(qb_f, kb_f, cb_f, rel, attno);

    // fc + BN(train) + relu*scale + residual into h1m
    gemm(attno, fcw, fcb, nullptr, fco, M_, 512, 512, 512, 512, 0, 0, 0);
    bn_stats<<<512, 256, 0, stream>>>(fco, stats);
    bn_apply<<<(M_ * 512 + 255) / 256, 256, 0, stream>>>(fco, stats, bng, bnb, ascl, h1m);

    // final projection -> d_out [b][128][t] fp32
    gemm(h1m, outw, outb, nullptr, out, M_, 128, 512, 512, 0, 0, 1, 0);
}

// Round 6
// 5006.007 us; speedup vs baseline: 3.8072x; 1.1702x over previous
//
#include <hip/hip_runtime.h>
#include <cstdint>
#include <cmath>

typedef unsigned short u16;
typedef unsigned int u32;

// ---- model dims ----
#define B_    8
#define T_IN  2048
#define CIN1  273
#define L1_   1025
#define L_    513
#define C_    512
#define CE_   576
#define M1_   (B_*L1_)   /* 8200 */
#define M_    (B_*L_)    /* 4104 */
#define K1_   (CIN1*4)   /* 1092 */
#define H_    8
#define D_    64
#define R_    50

// ======================= generic GEMM: C[m,n] = sum_k A[m,k]*B[n,k] + bias =======================
// amode: 0 = fp32 row-major A (lda), 2 = conv1 im2col from meg, 3 = conv2 im2col from x1,
//        4 = time-major h [t][b][c] read as A[m=b*L+t][k=c]
// cmode: 0 = C[m*ldc+n]; 1 = out[b][n][t] (n<128); 2 = C[(t*8+b)*ldc+n] (time-major)
__device__ __forceinline__ float a_load(const void* A, int m, int k, int lda, int amode) {
    if (amode == 0) {
        return ((const float*)A)[(size_t)m * lda + k];
    } else if (amode == 2) {
        int b = m / L1_, t = m - b * L1_;
        int ci = k >> 2, kk = k & 3;
        int it = 2 * t - 2 + kk;
        if ((unsigned)it >= (unsigned)T_IN) return 0.f;
        return ((const float*)A)[((size_t)(b * CIN1 + ci)) * T_IN + it];
    } else if (amode == 3) {
        int b = m / L_, t = m - b * L_;
        int ci = k >> 2, kk = k & 3;
        int it = 2 * t - 2 + kk;
        if ((unsigned)it >= (unsigned)L1_) return 0.f;
        return ((const float*)A)[((size_t)(b * L1_ + it)) * C_ + ci];
    } else {
        int b = m / L_, t = m - b * L_;
        return ((const float*)A)[((size_t)(t * 8 + b)) * C_ + k];
    }
}

__global__ __launch_bounds__(256) void gemm_kernel(
    const void* __restrict__ Aptr, const float* __restrict__ Bptr,
    const float* __restrict__ bias1, const float* __restrict__ bias2,
    float* __restrict__ Cf,
    int Msz, int Nsz, int Ksz, int lda, int ldc, int amode, int cmode, int relu)
{
    __shared__ float As[16][68];
    __shared__ float Bs[16][68];
    int tid = threadIdx.x;
    int tx = tid & 15, ty = tid >> 4;
    int kq = tid & 15, mq = tid >> 4;
    int m0 = blockIdx.x * 64, n0 = blockIdx.y * 64;

    float acc[4][4];
#pragma unroll
    for (int i = 0; i < 4; ++i)
#pragma unroll
        for (int j = 0; j < 4; ++j) acc[i][j] = 0.f;

    for (int k0 = 0; k0 < Ksz; k0 += 16) {
        int k = k0 + kq;
#pragma unroll
        for (int j = 0; j < 4; ++j) {
            int rl = mq + 16 * j;
            int m = m0 + rl;
            float av = 0.f;
            if (m < Msz && k < Ksz) av = a_load(Aptr, m, k, lda, amode);
            As[kq][rl] = av;
            float bv = 0.f;
            if (k < Ksz) bv = Bptr[(size_t)(n0 + rl) * Ksz + k];
            Bs[kq][rl] = bv;
        }
        __syncthreads();
#pragma unroll
        for (int kk = 0; kk < 16; ++kk) {
            float a4[4], b4[4];
            *(float4*)a4 = *(const float4*)&As[kk][ty * 4];
            *(float4*)b4 = *(const float4*)&Bs[kk][tx * 4];
#pragma unroll
            for (int i = 0; i < 4; ++i)
#pragma unroll
                for (int j = 0; j < 4; ++j) acc[i][j] += a4[i] * b4[j];
        }
        __syncthreads();
    }

#pragma unroll
    for (int i = 0; i < 4; ++i) {
        int m = m0 + ty * 4 + i;
        if (m >= Msz) continue;
#pragma unroll
        for (int j = 0; j < 4; ++j) {
            int n = n0 + tx * 4 + j;
            float v = acc[i][j] + bias1[n] + (bias2 ? bias2[n] : 0.f);
            if (relu) v = fmaxf(v, 0.f);
            if (cmode == 0) {
                Cf[(size_t)m * ldc + n] = v;
            } else if (cmode == 1) {
                int b = m / L_, t = m - b * L_;
                Cf[((size_t)(b * 128 + n)) * L_ + t] = v;
            } else {
                int b = m / L_, t = m - b * L_;
                Cf[((size_t)(t * 8 + b)) * ldc + n] = v;
            }
        }
    }
}

// ======================= subject embedding concat =======================
__global__ __launch_bounds__(256) void emb_kernel(const float* __restrict__ semb,
                                                  const int* __restrict__ subj,
                                                  float* __restrict__ x2bt)
{
    int idx = blockIdx.x * 256 + threadIdx.x;
    if (idx >= M_ * 64) return;
    int m = idx >> 6, e = idx & 63;
    int b = m / L_;
    x2bt[(size_t)m * CE_ + 512 + e] = semb[subj[b] * 64 + e];
}

// ======================= weight pack: fp32 [2048][512] -> bf16x2 u32 =======================
// layout: P[j][g][i2][lane][r], flat = ((j*4+g)*2+i2)*128 + lane*2 + r.
// word holds (W[g*512+j][c0], W[g*512+j][c0+1]) with c0 = 4*(lane+64*i2) + 2*r.
__device__ __forceinline__ u32 f2bf_rne(float f) {
    u32 x = __float_as_uint(f);
    return (x + 0x7fffu + ((x >> 16) & 1u)) >> 16;
}
__global__ __launch_bounds__(256) void pack_w(const float* __restrict__ W, u32* __restrict__ P)
{
    int gid = blockIdx.x * 256 + threadIdx.x;   // 524288 total
    int r = gid & 1, lane = (gid >> 1) & 63, i2 = (gid >> 7) & 1;
    int g = (gid >> 8) & 3, j = gid >> 10;
    int row = g * 512 + j;
    int c0 = 4 * (lane + 64 * i2) + 2 * r;
    u32 lo = f2bf_rne(W[(size_t)row * 512 + c0]);
    u32 hi = f2bf_rne(W[(size_t)row * 512 + c0 + 1]);
    P[gid] = lo | (hi << 16);
}

// ======================= fused 2-layer LSTM step (wide streaming loads) =======================
// Launch t = 0..L_: blocks 0..127 = layer0 step t, blocks 128..255 = layer1 step t-1.
// Wave rg owns hidden unit j = blk*4+rg (all 4 gates, all 8 batches); lane covers 4 c per i2.
// h layout [t][b][c]. pre0[(t*8+b)*2048 + g*512+j] has x@Wih0 + bih0 + bhh0.
__global__ __launch_bounds__(256, 1) void lstm_step_fused(
    const float* __restrict__ pre0,
    const u32* __restrict__ P0,    // Whh0 packed
    const u32* __restrict__ P1,    // Wih1 packed
    const u32* __restrict__ P2,    // Whh1 packed
    const float* __restrict__ bih1,
    const float* __restrict__ bhh1,
    float* __restrict__ h0seq,
    float* __restrict__ h1seq,
    float* __restrict__ c0st, float* __restrict__ c1st,
    int t)
{
    int layer = blockIdx.x >> 7;
    int blk = blockIdx.x & 127;
    if (layer == 0 && t >= L_) return;
    if (layer == 1 && t == 0) return;
    int tt = layer ? (t - 1) : t;

    int tid = threadIdx.x;
    int l  = tid & 63;         // lane
    int rg = tid >> 6;         // wave = hidden-unit offset
    int j = blk * 4 + rg;

    __shared__ float part[4 * 8 * 33];    // [rg*8+p][x=g*8+b], stride 33
    __shared__ float gates[4 * 33];       // [rg][x], stride 33

    float acc[4][8];
#pragma unroll
    for (int g = 0; g < 4; ++g)
#pragma unroll
        for (int b = 0; b < 8; ++b) acc[g][b] = 0.f;

    // ---- recurrent matvec: dwordx2 weights + float4 h, both fully coalesced ----
    const float* hAbase = (layer ? h1seq : h0seq) + (size_t)(tt - 1) * 4096;
    const u32* wA = (layer ? P2 : P0) + (size_t)j * 1024;
    if (tt > 0) {
#pragma unroll
        for (int i2 = 0; i2 < 2; ++i2) {
            int coff = 4 * (l + 64 * i2);
            float4 hv[8];
#pragma unroll
            for (int b = 0; b < 8; ++b)
                hv[b] = *(const float4*)&hAbase[b * 512 + coff];
#pragma unroll
            for (int g = 0; g < 4; ++g) {
                uint2 ww = *(const uint2*)&wA[(g * 2 + i2) * 128 + l * 2];
                float w0 = __uint_as_float(ww.x << 16);
                float w1 = __uint_as_float(ww.x & 0xffff0000u);
                float w2 = __uint_as_float(ww.y << 16);
                float w3 = __uint_as_float(ww.y & 0xffff0000u);
#pragma unroll
                for (int b = 0; b < 8; ++b)
                    acc[g][b] = fmaf(w0, hv[b].x, fmaf(w1, hv[b].y,
                                fmaf(w2, hv[b].z, fmaf(w3, hv[b].w, acc[g][b]))));
            }
        }
    }
    // ---- layer1 input-side matvec: Wih1 @ h0(tt) ----
    if (layer) {
        const float* hBbase = h0seq + (size_t)tt * 4096;
        const u32* wB = P1 + (size_t)j * 1024;
#pragma unroll
        for (int i2 = 0; i2 < 2; ++i2) {
            int coff = 4 * (l + 64 * i2);
            float4 hv[8];
#pragma unroll
            for (int b = 0; b < 8; ++b)
                hv[b] = *(const float4*)&hBbase[b * 512 + coff];
#pragma unroll
            for (int g = 0; g < 4; ++g) {
                uint2 ww = *(const uint2*)&wB[(g * 2 + i2) * 128 + l * 2];
                float w0 = __uint_as_float(ww.x << 16);
                float w1 = __uint_as_float(ww.x & 0xffff0000u);
                float w2 = __uint_as_float(ww.y << 16);
                float w3 = __uint_as_float(ww.y & 0xffff0000u);
#pragma unroll
                for (int b = 0; b < 8; ++b)
                    acc[g][b] = fmaf(w0, hv[b].x, fmaf(w1, hv[b].y,
                                fmaf(w2, hv[b].z, fmaf(w3, hv[b].w, acc[g][b]))));
            }
        }
    }

    // ---- reduce over lanes: 3-level butterfly (bits 3..5), lanes 0..7 hold partials ----
#pragma unroll
    for (int m = 8; m <= 32; m <<= 1)
#pragma unroll
        for (int g = 0; g < 4; ++g)
#pragma unroll
            for (int b = 0; b < 8; ++b)
                acc[g][b] += __shfl_xor(acc[g][b], m);
    if (l < 8) {
#pragma unroll
        for (int g = 0; g < 4; ++g)
#pragma unroll
            for (int b = 0; b < 8; ++b)
                part[(rg * 8 + l) * 33 + g * 8 + b] = acc[g][b];
    }
    __syncthreads();

    // ---- sum 8 partials + x-side, store gates ----
    if (tid < 128) {
        int w = tid >> 5, x = tid & 31;
        int g = x >> 3, b = x & 7;
        float s = 0.f;
#pragma unroll
        for (int p = 0; p < 8; ++p) s += part[(w * 8 + p) * 33 + x];
        int grow = g * 512 + blk * 4 + w;
        s += layer ? (bih1[grow] + bhh1[grow])
                   : pre0[((size_t)(tt * 8 + b)) * 2048 + grow];
        gates[w * 33 + x] = s;
    }
    __syncthreads();

    // ---- gate math + writes ----
    if (tid < 32) {
        int w = tid >> 3, b = tid & 7;
        float gi = gates[w * 33 + 0 * 8 + b];
        float gf = gates[w * 33 + 1 * 8 + b];
        float gg = gates[w * 33 + 2 * 8 + b];
        float go = gates[w * 33 + 3 * 8 + b];
        float* cst = layer ? c1st : c0st;
        int ji = blk * 4 + w;
        int ci = b * 512 + ji;
        float cprev = (tt == 0) ? 0.f : cst[ci];
        float si = 1.f / (1.f + expf(-gi));
        float sf = 1.f / (1.f + expf(-gf));
        float so = 1.f / (1.f + expf(-go));
        float cn = sf * cprev + si * tanhf(gg);
        cst[ci] = cn;
        float* hout = layer ? h1seq : h0seq;
        hout[((size_t)tt * 8 + b) * 512 + ji] = so * tanhf(cn);
    }
}

// ======================= banded attention (radius 50) =======================
__global__ __launch_bounds__(128) void attn_kernel(const float* __restrict__ q,
                                                   const float* __restrict__ k,
                                                   const float* __restrict__ cnt,
                                                   const float* __restrict__ rel,
                                                   float* __restrict__ out)
{
    int t = blockIdx.x, h = blockIdx.y, b = blockIdx.z;
    int s_lo = max(0, t - R_), s_hi = min(L_ - 1, t + R_);
    int W = s_hi - s_lo + 1;
    int tid = threadIdx.x;

    __shared__ float qrow[64];
    __shared__ float dots[104];
    __shared__ float red[128];

    const float* qp = q + ((size_t)(b * L_ + t) * C_ + h * D_);
    if (tid < 64) qrow[tid] = qp[tid];
    __syncthreads();

    if (tid < W) {
        int s = s_lo + tid;
        const float* kp = k + ((size_t)(b * L_ + s) * C_ + h * D_);
        const float* rp = rel + (R_ + t - s) * D_;
        float acc = 0.f;
#pragma unroll 8
        for (int d = 0; d < 64; ++d)
            acc += qrow[d] * (kp[d] + 0.3f * rp[d]);
        dots[tid] = acc;
    }
    __syncthreads();

    red[tid] = (tid < W) ? dots[tid] : -INFINITY;
    __syncthreads();
    for (int s = 64; s > 0; s >>= 1) {
        if (tid < s) red[tid] = fmaxf(red[tid], red[tid + s]);
        __syncthreads();
    }
    float mx = red[0];
    __syncthreads();
    float e = 0.f;
    if (tid < W) { e = expf(dots[tid] - mx); dots[tid] = e; }
    red[tid] = e;
    __syncthreads();
    for (int s = 64; s > 0; s >>= 1) {
        if (tid < s) red[tid] += red[tid + s];
        __syncthreads();
    }
    float inv = 1.f / red[0];
    if (tid < W) dots[tid] *= inv;
    __syncthreads();

    if (tid < 64) {
        float acc = 0.f;
        const float* cb = cnt + ((size_t)(b * L_ + s_lo) * C_ + h * D_ + tid);
        const float* rb = rel + (R_ + t - s_lo) * D_ + tid;
        for (int i = 0; i < W; ++i)
            acc += dots[i] * (cb[(size_t)i * C_] + 0.3f * rb[-i * D_]);
        out[(size_t)(b * L_ + t) * C_ + h * D_ + tid] = acc;
    }
}

// ======================= BatchNorm training stats =======================
__global__ __launch_bounds__(256) void bn_stats(const float* __restrict__ fcout, float* __restrict__ stats)
{
    int o = blockIdx.x;
    int tid = threadIdx.x;
    float s = 0.f, ss = 0.f;
    for (int m = tid; m < M_; m += 256) {
        float v = fcout[(size_t)m * 512 + o];
        s += v; ss += v * v;
    }
    __shared__ float rs[256], rq[256];
    rs[tid] = s; rq[tid] = ss;
    __syncthreads();
    for (int k = 128; k > 0; k >>= 1) {
        if (tid < k) { rs[tid] += rs[tid + k]; rq[tid] += rq[tid + k]; }
        __syncthreads();
    }
    if (tid == 0) {
        float mean = rs[0] / (float)M_;
        float var = rq[0] / (float)M_ - mean * mean;
        stats[o] = mean;
        stats[512 + o] = rsqrtf(fmaxf(var, 0.f) + 1e-5f);
    }
}

// ======================= BN apply + ReLU*scale + residual (h1 time-major -> xfin batch-major) ====
__global__ __launch_bounds__(256) void bn_apply(const float* __restrict__ fcout,
                                                const float* __restrict__ stats,
                                                const float* __restrict__ bng, const float* __restrict__ bnb,
                                                const float* __restrict__ ascl,
                                                const float* __restrict__ h1tm,
                                                float* __restrict__ xfin)
{
    int idx = blockIdx.x * 256 + threadIdx.x;
    if (idx >= M_ * 512) return;
    int c = idx & 511;
    int m = idx >> 9;
    int b = m / L_, t = m - b * L_;
    float v = (fcout[idx] - stats[c]) * stats[512 + c] * bng[c] + bnb[c];
    v = fmaxf(v, 0.f) * ascl[c];
    xfin[idx] = h1tm[((size_t)(t * 8 + b)) * 512 + c] + v;
}

// ======================= host launch =======================
extern "C" void kernel_launch(void* const* d_in, const int* in_sizes, int n_in,
                              void* d_out, int out_size, void* d_ws, size_t ws_size,
                              hipStream_t stream)
{
    const float* meg  = (const float*)d_in[0];
    const float* w1   = (const float*)d_in[1];
    const float* b1   = (const float*)d_in[2];
    const float* w2   = (const float*)d_in[3];
    const float* b2   = (const float*)d_in[4];
    const float* semb = (const float*)d_in[5];
    const float* Wih0 = (const float*)d_in[6];
    const float* Whh0 = (const float*)d_in[7];
    const float* bih0 = (const float*)d_in[8];
    const float* bhh0 = (const float*)d_in[9];
    const float* Wih1 = (const float*)d_in[10];
    const float* Whh1 = (const float*)d_in[11];
    const float* bih1 = (const float*)d_in[12];
    const float* bhh1 = (const float*)d_in[13];
    const float* qw   = (const float*)d_in[14];
    const float* qb   = (const float*)d_in[15];
    const float* kw   = (const float*)d_in[16];
    const float* kb   = (const float*)d_in[17];
    const float* cw   = (const float*)d_in[18];
    const float* cbi  = (const float*)d_in[19];
    const float* rel  = (const float*)d_in[20];
    const float* fcw  = (const float*)d_in[21];
    const float* fcb  = (const float*)d_in[22];
    const float* bng  = (const float*)d_in[23];
    const float* bnb  = (const float*)d_in[24];
    const float* ascl = (const float*)d_in[25];
    const float* outw = (const float*)d_in[26];
    const float* outb = (const float*)d_in[27];
    const int* subj = (const int*)d_in[28];
    float* out = (float*)d_out;

    float* ws = (float*)d_ws;
    // arena (float offsets)
    float* x1    = ws + 0;          // [8200][512] conv phase only -> 4,198,400
    // LSTM-phase overlays of the dead x1 region:
    u32*   P0    = (u32*)(ws + 0);        // Whh0 bf16 packed: 524,288 words
    u32*   P1    = (u32*)(ws + 524288);   // Wih1
    u32*   P2    = (u32*)(ws + 1048576);  // Whh1
    float* c0    = ws + 1572864;    // [8][512] cell state L0
    float* c1    = ws + 1576960;    // [8][512] cell state L1
    float* x2bt  = ws + 4198400;    // [4104][576]                 -> 6,562,304
    float* pre0  = ws + 6562304;    // [(t*8+b)][2048]             -> 14,967,296
    float* h0    = ws + 14967296;   // [t][b][c]                   -> 17,068,544
    float* h1    = ws + 17068544;   // [t][b][c]                   -> 19,169,792
    float* xfin  = ws + 19169792;   // [b*L+t][c] final residual   -> 21,271,040
    // post-LSTM overlays:
    float* qb_f  = ws + 0;          // q  [4104][512]
    float* kb_f  = ws + 2101248;    // k
    float* cb_f  = ws + 4202496;    // cnt (spills into dead x2bt region)
    float* attno = ws + 6562304;    // over pre0
    float* fco   = ws + 8663552;
    float* stats = ws + 10764800;   // 1024 floats

    auto gemm = [&](const void* A, const float* Bw, const float* bi1, const float* bi2,
                    float* Cf, int Msz, int Nsz, int Ksz,
                    int lda, int ldc, int amode, int cmode, int relu) {
        dim3 g((Msz + 63) / 64, Nsz / 64);
        gemm_kernel<<<g, 256, 0, stream>>>(A, Bw, bi1, bi2, Cf,
                                           Msz, Nsz, Ksz, lda, ldc, amode, cmode, relu);
    };

    // conv1 (im2col from meg) -> x1 [b*1025+t][512], relu
    gemm(meg, w1, b1, nullptr, x1, M1_, 512, K1_, 0, 512, 2, 0, 1);
    // conv2 (im2col from x1) -> x2bt [b*513+t][576] cols 0..511, relu
    gemm(x1, w2, b2, nullptr, x2bt, M_, 512, 2048, 0, CE_, 3, 0, 1);
    // subject embedding -> cols 512..575
    emb_kernel<<<(M_ * 64 + 255) / 256, 256, 0, stream>>>(semb, subj, x2bt);

    // pack LSTM weights to bf16 (x1 region is dead now)
    pack_w<<<2048, 256, 0, stream>>>(Whh0, P0);
    pack_w<<<2048, 256, 0, stream>>>(Wih1, P1);
    pack_w<<<2048, 256, 0, stream>>>(Whh1, P2);

    // layer-0 x-projection (time-major output, both biases folded)
    gemm(x2bt, Wih0, bih0, bhh0, pre0, M_, 2048, CE_, CE_, 2048, 0, 2, 0);

    // fused 2-layer LSTM: layer0 step t + layer1 step t-1 per launch
    for (int t = 0; t <= L_; ++t)
        lstm_step_fused<<<256, 256, 0, stream>>>(pre0, P0, P1, P2, bih1, bhh1,
                                                 h0, h1, c0, c1, t);

    // attention projections (read h1 time-major via amode=4)
    gemm(h1, qw, qb, nullptr, qb_f, M_, 512, 512, 512, 512, 4, 0, 0);
    gemm(h1, kw, kb, nullptr, kb_f, M_, 512, 512, 512, 512, 4, 0, 0);
    gemm(h1, cw, cbi, nullptr, cb_f, M_, 512, 512, 512, 512, 4, 0, 0);

    attn_kernel<<<dim3(L_, H_, B_), 128, 0, stream>>>(qb_f, kb_f, cb_f, rel, attno);

    // fc + BN(train) + relu*scale + residual -> xfin (batch-major)
    gemm(attno, fcw, fcb, nullptr, fco, M_, 512, 512, 512, 512, 0, 0, 0);
    bn_stats<<<512, 256, 0, stream>>>(fco, stats);
    bn_apply<<<(M_ * 512 + 255) / 256, 256, 0, stream>>>(fco, stats, bng, bnb, ascl, h1, xfin);

    // final projection -> d_out [b][128][t] fp32
    gemm(xfin, outw, outb, nullptr, out, M_, 128, 512, 512, 0, 0, 1, 0);
}